// Round 18
// baseline (779.268 us; speedup 1.0000x reference)
//
#include <hip/hip_runtime.h>
#include <hip/hip_bf16.h>

#define NN 50000   // nodes
#define EE 800000  // directed edges (no self loops)
#define ET 850000  // EE + NN self loops
#define GG 1024    // graphs
#define DD 128     // embedding dim
#define HH 4       // heads
#define LL 3       // layers
#define ND 78      // node feature dim
#define HD 512     // HH*DD
#define K1P 96     // node-dim padded to multiple of 32 for MFMA
#define SLOPE 0.2f
#define EPSV 1e-16f
#define SB 196     // scan blocks = ceil(NN/256)
#define PADS 520   // LDS row stride in shorts (512 + 8 pad)

typedef __hip_bfloat16 bf16;
typedef __attribute__((ext_vector_type(8))) unsigned short u16x8;
typedef __attribute__((ext_vector_type(8))) short s16x8;   // MFMA A/B fragment (8 bf16)
typedef __attribute__((ext_vector_type(4))) float f32x4;   // MFMA C/D fragment

__device__ __forceinline__ float b2f(bf16 v) { return __bfloat162float(v); }
__device__ __forceinline__ bf16 f2b(float v) { return __float2bfloat16(v); }
__device__ __forceinline__ float bu2f(unsigned short u) {
    return __uint_as_float(((unsigned)u) << 16);
}
__device__ __forceinline__ unsigned short f2bu(float f) {
    unsigned u = __float_as_uint(f);
    unsigned rounded = u + 0x7FFFu + ((u >> 16) & 1u);
    return (unsigned short)(rounded >> 16);
}

// ---------------- int width detection (int64 vs int32) ----------------
__global__ void detect_i(const unsigned* __restrict__ w, int* __restrict__ flag) {
    __shared__ int z;
    int t = threadIdx.x;  // 256
    if (t == 0) z = 0;
    __syncthreads();
    if (w[2 * t + 1] == 0u) atomicAdd(&z, 1);
    __syncthreads();
    if (t == 0) flag[0] = (z >= 200) ? 1 : 0;
}
__global__ void conv_i(const void* __restrict__ src, int* __restrict__ dst, int n,
                       const int* __restrict__ flag) {
    int i = blockIdx.x * 256 + threadIdx.x;
    if (i >= n) return;
    const int* s = (const int*)src;
    dst[i] = flag[0] ? s[2 * i] : s[i];
}

// ---------------- x -> bf16, zero-padded to K1P ----------------
__global__ void xconv(const float* __restrict__ x, bf16* __restrict__ xb) {
    int idx = blockIdx.x * 256 + threadIdx.x;
    if (idx >= NN * K1P) return;
    int n = idx / K1P;
    int k = idx % K1P;
    xb[idx] = f2b((k < ND) ? x[(size_t)n * ND + k] : 0.f);
}
// W1t[c][k<96] = W1[k][c] (zero-pad k>=78); W2t[c][k] = W2[k][c]; bf16
__global__ void nw_conv(const float* __restrict__ W1, const float* __restrict__ W2,
                        bf16* __restrict__ W1t, bf16* __restrict__ W2t) {
    int idx = blockIdx.x * 256 + threadIdx.x;
    if (idx < DD * K1P) {
        int c = idx / K1P, k = idx % K1P;
        W1t[idx] = f2b((k < ND) ? W1[(size_t)k * DD + c] : 0.f);
    }
    idx -= DD * K1P;
    if (idx >= 0 && idx < DD * DD) {
        int c = idx / DD, k = idx % DD;
        W2t[idx] = f2b(W2[(size_t)k * DD + c]);
    }
}

// ---------------- node MLP stage 1: ts = relu(xb[NN,96] @ W1t^T + b1), MFMA ----------------
__global__ __launch_bounds__(256) void mlp_gemm1(const bf16* __restrict__ xb,
                                                 const bf16* __restrict__ W1t,
                                                 const float* __restrict__ b1,
                                                 bf16* __restrict__ ts) {
    int wid = (blockIdx.x * 256 + threadIdx.x) >> 6;
    if (wid >= NN / 16) return;
    int lane = threadIdx.x & 63;
    int r16 = lane & 15;
    int q = lane >> 4;
    const short* ab = (const short*)xb;
    const short* bb = (const short*)W1t;
    int arow = wid * 16 + r16;
    s16x8 afr[3];
#pragma unroll
    for (int c = 0; c < 3; c++) afr[c] = *(const s16x8*)(ab + (size_t)arow * K1P + c * 32 + q * 8);
#pragma unroll
    for (int nt = 0; nt < 8; nt++) {
        int brow = nt * 16 + r16;
        f32x4 acc = {0.f, 0.f, 0.f, 0.f};
#pragma unroll
        for (int c = 0; c < 3; c++) {
            s16x8 b = *(const s16x8*)(bb + (size_t)brow * K1P + c * 32 + q * 8);
            acc = __builtin_amdgcn_mfma_f32_16x16x32_bf16(afr[c], b, acc, 0, 0, 0);
        }
        int cc = nt * 16 + r16;
        float bias = b1[cc];
#pragma unroll
        for (int r = 0; r < 4; r++) {
            int row = wid * 16 + q * 4 + r;
            ts[(size_t)row * DD + cc] = f2b(fmaxf(acc[r] + bias, 0.f));
        }
    }
}

// ---------------- node MLP stage 2: h = ts[NN,128] @ W2t^T + b2, MFMA ----------------
__global__ __launch_bounds__(256) void mlp_gemm2(const bf16* __restrict__ ts,
                                                 const bf16* __restrict__ W2t,
                                                 const float* __restrict__ b2,
                                                 bf16* __restrict__ h) {
    int wid = (blockIdx.x * 256 + threadIdx.x) >> 6;
    if (wid >= NN / 16) return;
    int lane = threadIdx.x & 63;
    int r16 = lane & 15;
    int q = lane >> 4;
    const short* ab = (const short*)ts;
    const short* bb = (const short*)W2t;
    int arow = wid * 16 + r16;
    s16x8 afr[4];
#pragma unroll
    for (int c = 0; c < 4; c++) afr[c] = *(const s16x8*)(ab + (size_t)arow * DD + c * 32 + q * 8);
#pragma unroll
    for (int nt = 0; nt < 8; nt++) {
        int brow = nt * 16 + r16;
        f32x4 acc = {0.f, 0.f, 0.f, 0.f};
#pragma unroll
        for (int c = 0; c < 4; c++) {
            s16x8 b = *(const s16x8*)(bb + (size_t)brow * DD + c * 32 + q * 8);
            acc = __builtin_amdgcn_mfma_f32_16x16x32_bf16(afr[c], b, acc, 0, 0, 0);
        }
        int cc = nt * 16 + r16;
        float bias = b2[cc];
#pragma unroll
        for (int r = 0; r < 4; r++) {
            int row = wid * 16 + q * 4 + r;
            h[(size_t)row * DD + cc] = f2b(acc[r] + bias);
        }
    }
}

// ---------------- counting sort of edges by dst (parallel 3-phase scan) ----------------
__global__ void init_deg(int* deg) {
    int n = blockIdx.x * 256 + threadIdx.x;
    if (n < NN) deg[n] = 1;  // self loop
}
__global__ void hist_edges(const int* __restrict__ ei, int* deg) {
    int e = blockIdx.x * 256 + threadIdx.x;
    if (e >= EE) return;
    int dst = ei[EE + e];
    if ((unsigned)dst < NN) atomicAdd(&deg[dst], 1);
}
__global__ __launch_bounds__(256) void block_sums(const int* __restrict__ deg, int* __restrict__ bsum) {
    __shared__ int part[256];
    int t = threadIdx.x;
    int i = blockIdx.x * 256 + t;
    part[t] = (i < NN) ? deg[i] : 0;
    __syncthreads();
    for (int off = 128; off > 0; off >>= 1) {
        if (t < off) part[t] += part[t + off];
        __syncthreads();
    }
    if (t == 0) bsum[blockIdx.x] = part[0];
}
__global__ __launch_bounds__(256) void scan_bsum(const int* __restrict__ bsum, int* __restrict__ boff,
                                                 int* __restrict__ start) {
    __shared__ int part[256];
    int t = threadIdx.x;
    part[t] = (t < SB) ? bsum[t] : 0;
    __syncthreads();
    for (int off = 1; off < 256; off <<= 1) {
        int add = (t >= off) ? part[t - off] : 0;
        __syncthreads();
        part[t] += add;
        __syncthreads();
    }
    if (t < SB) boff[t] = (t == 0) ? 0 : part[t - 1];
    if (t == 255) start[NN] = part[SB - 1];
}
__global__ __launch_bounds__(256) void scan_final(const int* __restrict__ deg, const int* __restrict__ boff,
                                                  int* __restrict__ start, int* __restrict__ cursor) {
    __shared__ int part[256];
    int t = threadIdx.x;
    int i = blockIdx.x * 256 + t;
    int v = (i < NN) ? deg[i] : 0;
    part[t] = v;
    __syncthreads();
    for (int off = 1; off < 256; off <<= 1) {
        int add = (t >= off) ? part[t - off] : 0;
        __syncthreads();
        part[t] += add;
        __syncthreads();
    }
    if (i < NN) {
        int ex = boff[blockIdx.x] + part[t] - v;
        start[i] = ex;
        cursor[i] = ex;
    }
}
__global__ void scatter_self(int* cursor, int* ssrc) {
    int n = blockIdx.x * 256 + threadIdx.x;
    if (n >= NN) return;
    int pos = atomicAdd(&cursor[n], 1);
    if ((unsigned)pos < ET) ssrc[pos] = n;
}
__global__ void scatter_edges(const int* __restrict__ ei, int* cursor, int* ssrc) {
    int e = blockIdx.x * 256 + threadIdx.x;
    if (e >= EE) return;
    int src = ei[e];
    int dst = ei[EE + e];
    if ((unsigned)dst >= NN) return;
    int pos = atomicAdd(&cursor[dst], 1);
    if ((unsigned)pos < ET) ssrc[pos] = ((unsigned)src < NN) ? src : 0;
}

// ---------------- precompute ws/wd [L][D][H] ----------------
__global__ void asd_w(const float* __restrict__ lin_w, const float* __restrict__ att_src,
                      const float* __restrict__ att_dst,
                      float* __restrict__ ws, float* __restrict__ wd) {
    int idx = blockIdx.x * 256 + threadIdx.x;
    if (idx >= LL * DD * HH) return;
    int l = idx / (DD * HH);
    int rem = idx % (DD * HH);
    int d = rem >> 2;
    int h = rem & 3;
    const float* wrow = lin_w + ((size_t)(l * DD + d) * HH + h) * DD;
    const float* as = att_src + (size_t)(l * HH + h) * DD;
    const float* ad = att_dst + (size_t)(l * HH + h) * DD;
    float s1 = 0.f, s2 = 0.f;
    for (int e = 0; e < DD; e++) { float w = wrow[e]; s1 += w * as[e]; s2 += w * ad[e]; }
    ws[idx] = s1;
    wd[idx] = s2;
}

// ---------------- Bt[l][c][k=h*128+d] = lin_w[l][d][h][c], bf16 ----------------
__global__ void wt2_conv(const float* __restrict__ lin_w, bf16* __restrict__ Bt) {
    int idx = blockIdx.x * 256 + threadIdx.x;
    if (idx >= LL * DD * HD) return;
    int l = idx / (DD * HD);
    int rem = idx % (DD * HD);
    int c = rem / HD;
    int k = rem % HD;
    int h = k >> 7;
    int d = k & 127;
    Bt[idx] = f2b(lin_w[((size_t)(l * DD + d) * HH + h) * DD + c]);
}

// ---------------- gW1t/gW2t transposes (bf16) ----------------
__global__ void gw_conv(const float* __restrict__ gW1, const float* __restrict__ gW2,
                        bf16* __restrict__ gW1t, bf16* __restrict__ gW2t) {
    int idx = blockIdx.x * 256 + threadIdx.x;
    if (idx < 1024 * DD) {
        int c = idx / DD, k = idx % DD;
        gW1t[idx] = f2b(gW1[(size_t)k * 1024 + c]);
    }
    idx -= 1024 * DD;
    if (idx >= 0 && idx < DD * 1024) {
        int c = idx / 1024, k = idx % 1024;
        gW2t[idx] = f2b(gW2[(size_t)k * DD + c]);
    }
}

// ---------------- a_s,a_d from h: one thread per node ----------------
__global__ __launch_bounds__(256) void a_sd2(const bf16* __restrict__ h,
                                             const float* __restrict__ ws,
                                             const float* __restrict__ wd,
                                             float* __restrict__ a_s, float* __restrict__ a_d) {
    __shared__ float wsl[DD][HH];
    __shared__ float wdl[DD][HH];
    int t = threadIdx.x;
    for (int i = t; i < DD * HH; i += 256) { wsl[i >> 2][i & 3] = ws[i]; wdl[i >> 2][i & 3] = wd[i]; }
    __syncthreads();
    int n = blockIdx.x * 256 + t;
    if (n >= NN) return;
    const u16x8* row = (const u16x8*)((const unsigned short*)h + (size_t)n * DD);
    float s1[HH] = {0.f, 0.f, 0.f, 0.f};
    float s2[HH] = {0.f, 0.f, 0.f, 0.f};
    for (int c = 0; c < 16; c++) {
        u16x8 v = row[c];
#pragma unroll
        for (int k = 0; k < 8; k++) {
            int d = c * 8 + k;
            float f = bu2f(v[k]);
#pragma unroll
            for (int hh = 0; hh < HH; hh++) {
                s1[hh] += f * wsl[d][hh];
                s2[hh] += f * wdl[d][hh];
            }
        }
    }
#pragma unroll
    for (int hh = 0; hh < HH; hh++) {
        a_s[n * HH + hh] = s1[hh];
        a_d[n * HH + hh] = s2[hh];
    }
}

// ---------------- fused GAT layer: register softmax + aggregate + GEMM ----------------
// 1024 threads = 16 waves; wave wv owns node blockIdx*16+wv. Fast path (deg<=64):
// lane j owns edge j: gathers a_s4[src_j] (reusing the coalesced sidx load),
// computes leaky score; per-head max/den via 6 shfl_xor rounds; FMA loop pulls
// w via __shfl(wgt[h], j) — no wbuf, no extra LDS, no extra barriers. General
// two-pass fallback for deg>64. Then 16x16x512 MFMA col tiles from LDS.
__global__ __launch_bounds__(1024) void agg_gemm(const int* __restrict__ start,
                                                 const int* __restrict__ ssrc,
                                                 const float* __restrict__ a_s,
                                                 const float* __restrict__ a_d,
                                                 const bf16* __restrict__ h,
                                                 const bf16* __restrict__ Bt,
                                                 const float* __restrict__ conv_b,
                                                 bf16* __restrict__ hnext) {
    __shared__ short aggL[16 * PADS];   // 16 rows x 512 (+8 pad) bf16
    int wv = threadIdx.x >> 6;          // 0..15
    int lane = threadIdx.x & 63;
    int node16 = blockIdx.x * 16;
    int node = node16 + wv;             // NN % 16 == 0 -> always valid

    int s0 = start[node];
    int deg = start[node + 1] - s0;     // >= 1 (self loop)
    const unsigned* hu = (const unsigned*)h;
    float4 ad4 = *(const float4*)(a_d + (size_t)node * HH);   // wave-uniform

    float acc[HH][2];
#pragma unroll
    for (int hh = 0; hh < HH; hh++) { acc[hh][0] = 0.f; acc[hh][1] = 0.f; }
    float inv[HH];

    auto fmaEdge = [&](float4 w4, unsigned hv) {
        float v0 = bu2f((unsigned short)(hv & 0xFFFFu));
        float v1 = bu2f((unsigned short)(hv >> 16));
        acc[0][0] += w4.x * v0; acc[0][1] += w4.x * v1;
        acc[1][0] += w4.y * v0; acc[1][1] += w4.y * v1;
        acc[2][0] += w4.z * v0; acc[2][1] += w4.z * v1;
        acc[3][0] += w4.w * v0; acc[3][1] += w4.w * v1;
    };
    auto leaky = [](float e) { return (e > 0.f) ? e : SLOPE * e; };

    if (deg <= 64) {
        // ---- fast path: one edge per lane, everything in registers ----
        int sidx = (lane < deg) ? ssrc[s0 + lane] : 0;
        float4 as4 = *(const float4*)(a_s + (size_t)sidx * HH);   // random 16B gather
        float e[HH] = {leaky(as4.x + ad4.x), leaky(as4.y + ad4.y),
                       leaky(as4.z + ad4.z), leaky(as4.w + ad4.w)};
        if (lane >= deg) { e[0] = e[1] = e[2] = e[3] = -1e30f; }
        float mx[HH] = {e[0], e[1], e[2], e[3]};
#pragma unroll
        for (int off = 1; off < 64; off <<= 1) {
#pragma unroll
            for (int hh = 0; hh < HH; hh++) mx[hh] = fmaxf(mx[hh], __shfl_xor(mx[hh], off));
        }
        float wgt[HH];
#pragma unroll
        for (int hh = 0; hh < HH; hh++) wgt[hh] = (lane < deg) ? __expf(e[hh] - mx[hh]) : 0.f;
        float den[HH] = {wgt[0], wgt[1], wgt[2], wgt[3]};
#pragma unroll
        for (int off = 1; off < 64; off <<= 1) {
#pragma unroll
            for (int hh = 0; hh < HH; hh++) den[hh] += __shfl_xor(den[hh], off);
        }
#pragma unroll
        for (int hh = 0; hh < HH; hh++) inv[hh] = 1.f / (den[hh] + EPSV);

        int j = 0;
        for (; j + 4 <= deg; j += 4) {
#pragma unroll
            for (int k = 0; k < 4; k++) {
                int jk = j + k;
                int s = __shfl(sidx, jk);
                float4 w4 = make_float4(__shfl(wgt[0], jk), __shfl(wgt[1], jk),
                                        __shfl(wgt[2], jk), __shfl(wgt[3], jk));
                unsigned hv = hu[(size_t)s * (DD / 2) + lane];
                fmaEdge(w4, hv);
            }
        }
        for (; j < deg; j++) {
            int s = __shfl(sidx, j);
            float4 w4 = make_float4(__shfl(wgt[0], j), __shfl(wgt[1], j),
                                    __shfl(wgt[2], j), __shfl(wgt[3], j));
            unsigned hv = hu[(size_t)s * (DD / 2) + lane];
            fmaEdge(w4, hv);
        }
    } else {
        // ---- general two-pass fallback (deg > 64; rare) ----
        float emax[HH] = {-1e30f, -1e30f, -1e30f, -1e30f};
        for (int c0 = 0; c0 < deg; c0 += 64) {
            int valid = (c0 + lane < deg);
            int sidx = valid ? ssrc[s0 + c0 + lane] : 0;
            float4 as4 = *(const float4*)(a_s + (size_t)sidx * HH);
            float e0 = leaky(as4.x + ad4.x), e1 = leaky(as4.y + ad4.y);
            float e2 = leaky(as4.z + ad4.z), e3 = leaky(as4.w + ad4.w);
            if (!valid) { e0 = e1 = e2 = e3 = -1e30f; }
            emax[0] = fmaxf(emax[0], e0); emax[1] = fmaxf(emax[1], e1);
            emax[2] = fmaxf(emax[2], e2); emax[3] = fmaxf(emax[3], e3);
        }
#pragma unroll
        for (int off = 1; off < 64; off <<= 1) {
#pragma unroll
            for (int hh = 0; hh < HH; hh++) emax[hh] = fmaxf(emax[hh], __shfl_xor(emax[hh], off));
        }
        float den[HH] = {0.f, 0.f, 0.f, 0.f};
        for (int c0 = 0; c0 < deg; c0 += 64) {
            int m = deg - c0; if (m > 64) m = 64;
            int valid = (lane < m);
            int sidx = valid ? ssrc[s0 + c0 + lane] : 0;
            float4 as4 = *(const float4*)(a_s + (size_t)sidx * HH);
            float wgt[HH];
            wgt[0] = valid ? __expf(leaky(as4.x + ad4.x) - emax[0]) : 0.f;
            wgt[1] = valid ? __expf(leaky(as4.y + ad4.y) - emax[1]) : 0.f;
            wgt[2] = valid ? __expf(leaky(as4.z + ad4.z) - emax[2]) : 0.f;
            wgt[3] = valid ? __expf(leaky(as4.w + ad4.w) - emax[3]) : 0.f;
#pragma unroll
            for (int hh = 0; hh < HH; hh++) den[hh] += wgt[hh];
            for (int j = 0; j < m; j++) {
                int s = __shfl(sidx, j);
                float4 w4 = make_float4(__shfl(wgt[0], j), __shfl(wgt[1], j),
                                        __shfl(wgt[2], j), __shfl(wgt[3], j));
                unsigned hv = hu[(size_t)s * (DD / 2) + lane];
                fmaEdge(w4, hv);
            }
        }
#pragma unroll
        for (int off = 1; off < 64; off <<= 1) {
#pragma unroll
            for (int hh = 0; hh < HH; hh++) den[hh] += __shfl_xor(den[hh], off);
        }
#pragma unroll
        for (int hh = 0; hh < HH; hh++) inv[hh] = 1.f / (den[hh] + EPSV);
    }

    unsigned* aggU = (unsigned*)aggL;   // row stride PADS/2 = 260 uints
#pragma unroll
    for (int hh = 0; hh < HH; hh++) {
        unsigned packed = (unsigned)f2bu(acc[hh][0] * inv[hh]) |
                          ((unsigned)f2bu(acc[hh][1] * inv[hh]) << 16);
        aggU[wv * (PADS / 2) + hh * (DD / 2) + lane] = packed;
    }
    __syncthreads();

    // ---- GEMM phase: waves 0..7, one 16x16 col tile each ----
    if (wv < 8) {
        int nt = wv;
        int r16 = lane & 15;
        int q = lane >> 4;
        const short* bb = (const short*)Bt;
        int brow = nt * 16 + r16;
        f32x4 gacc = {0.f, 0.f, 0.f, 0.f};
#pragma unroll
        for (int c = 0; c < 16; c++) {
            s16x8 a = *(const s16x8*)(aggL + r16 * PADS + c * 32 + q * 8);
            s16x8 b = *(const s16x8*)(bb + (size_t)brow * HD + c * 32 + q * 8);
            gacc = __builtin_amdgcn_mfma_f32_16x16x32_bf16(a, b, gacc, 0, 0, 0);
        }
        int cc = nt * 16 + r16;
        float bias = conv_b[cc];
#pragma unroll
        for (int r = 0; r < 4; r++) {
            int row = node16 + q * 4 + r;
            hnext[(size_t)row * DD + cc] = f2b(0.25f * gacc[r] + bias);
        }
    }
}

// ---------------- global mean pool (segmented: batch is sorted) ----------------
__global__ void pool_init(float* pooled, int* counts) {
    int idx = blockIdx.x * 256 + threadIdx.x;
    if (idx < GG * DD) pooled[idx] = 0.f;
    if (idx < GG) counts[idx] = 0;
}
__global__ void pool_count(const int* __restrict__ batch, int* counts) {
    int n = blockIdx.x * 256 + threadIdx.x;
    if (n >= NN) return;
    int g = batch[n];
    if ((unsigned)g < GG) atomicAdd(&counts[g], 1);
}
__global__ __launch_bounds__(256) void pool_accum2(const bf16* __restrict__ h,
                                                   const int* __restrict__ batch,
                                                   float* pooled) {
    int t = threadIdx.x;
    int d = t & 127;
    int half = t >> 7;
    int n0 = blockIdx.x * 64 + half * 32;
    int n1 = n0 + 32; if (n1 > NN) n1 = NN;
    float acc = 0.f;
    int cur = -1;
    for (int n = n0; n < n1; n++) {
        int g = batch[n];
        if ((unsigned)g >= GG) continue;
        if (g != cur) {
            if (cur >= 0) atomicAdd(&pooled[cur * DD + d], acc);
            acc = 0.f; cur = g;
        }
        acc += b2f(h[(size_t)n * DD + d]);
    }
    if (cur >= 0) atomicAdd(&pooled[cur * DD + d], acc);
}
__global__ void pooled2bf(const float* __restrict__ pooled, const int* __restrict__ counts,
                          bf16* __restrict__ pbf) {
    int idx = blockIdx.x * 256 + threadIdx.x;
    if (idx >= GG * DD) return;
    int g = idx >> 7;
    int c = counts[g]; if (c < 1) c = 1;
    pbf[idx] = f2b(pooled[idx] / (float)c);
}

// ---------------- FC1 MFMA: t1 = relu(pbf[1024,128] @ gW1t^T + gb1), bf16 ----------------
__global__ __launch_bounds__(256) void fc1_mfma(const bf16* __restrict__ pbf,
                                                const bf16* __restrict__ gW1t,
                                                const float* __restrict__ gb1,
                                                bf16* __restrict__ t1) {
    int wid = (blockIdx.x * 256 + threadIdx.x) >> 6;  // 64*64 waves
    int lane = threadIdx.x & 63;
    int mt = wid >> 6;
    int nt = wid & 63;
    int r16 = lane & 15;
    int q = lane >> 4;
    const short* ab = (const short*)pbf;
    const short* bb = (const short*)gW1t;
    f32x4 acc = {0.f, 0.f, 0.f, 0.f};
    int arow = mt * 16 + r16;
    int brow = nt * 16 + r16;
#pragma unroll
    for (int c = 0; c < 4; c++) {
        s16x8 a = *(const s16x8*)(ab + (size_t)arow * DD + c * 32 + q * 8);
        s16x8 b = *(const s16x8*)(bb + (size_t)brow * DD + c * 32 + q * 8);
        acc = __builtin_amdgcn_mfma_f32_16x16x32_bf16(a, b, acc, 0, 0, 0);
    }
    int cc = nt * 16 + r16;
    float bias = gb1[cc];
#pragma unroll
    for (int r = 0; r < 4; r++) {
        int row = mt * 16 + q * 4 + r;
        t1[(size_t)row * 1024 + cc] = f2b(fmaxf(acc[r] + bias, 0.f));
    }
}

// ---------------- FC2 MFMA: out = t1[1024,1024] @ gW2t^T + gb2, f32 ----------------
__global__ __launch_bounds__(256) void fc2_mfma(const bf16* __restrict__ t1,
                                                const bf16* __restrict__ gW2t,
                                                const float* __restrict__ gb2,
                                                float* __restrict__ out) {
    int wid = (blockIdx.x * 256 + threadIdx.x) >> 6;  // 64*8 waves
    int lane = threadIdx.x & 63;
    int mt = wid >> 3;
    int nt = wid & 7;
    int r16 = lane & 15;
    int q = lane >> 4;
    const short* ab = (const short*)t1;
    const short* bb = (const short*)gW2t;
    f32x4 acc = {0.f, 0.f, 0.f, 0.f};
    int arow = mt * 16 + r16;
    int brow = nt * 16 + r16;
#pragma unroll
    for (int c = 0; c < 32; c++) {
        s16x8 a = *(const s16x8*)(ab + (size_t)arow * 1024 + c * 32 + q * 8);
        s16x8 b = *(const s16x8*)(bb + (size_t)brow * 1024 + c * 32 + q * 8);
        acc = __builtin_amdgcn_mfma_f32_16x16x32_bf16(a, b, acc, 0, 0, 0);
    }
    int cc = nt * 16 + r16;
    float bias = gb2[cc];
#pragma unroll
    for (int r = 0; r < 4; r++) {
        int row = mt * 16 + q * 4 + r;
        out[(size_t)row * DD + cc] = acc[r] + bias;
    }
}

__global__ void sentinel_only(float* out, int hostcode) {
    if (threadIdx.x == 0 && blockIdx.x == 0) out[0] = (float)hostcode;
}

extern "C" void kernel_launch(void* const* d_in, const int* in_sizes, int n_in,
                              void* d_out, int out_size, void* d_ws, size_t ws_size,
                              hipStream_t stream) {
    float* out = (float*)d_out;

    static const int expect[15] = {3900000, 1600000, 50000, 9984, 128, 16384, 128,
                                   196608, 1536, 1536, 384, 131072, 1024, 131072, 128};
    int hostcode = 0;
    if (n_in != 15) hostcode = 21099;
    else for (int i = 0; i < 15; i++) if (in_sizes[i] != expect[i]) { hostcode = 21000 + i; break; }
    if (hostcode == 0 && out_size != GG * DD) hostcode = 35000;

    const float* x       = (const float*)d_in[0];
    const float* W1      = (const float*)d_in[3];
    const float* b1      = (const float*)d_in[4];
    const float* W2      = (const float*)d_in[5];
    const float* b2      = (const float*)d_in[6];
    const float* lin_w   = (const float*)d_in[7];
    const float* att_src = (const float*)d_in[8];
    const float* att_dst = (const float*)d_in[9];
    const float* conv_b  = (const float*)d_in[10];
    const float* gW1     = (const float*)d_in[11];
    const float* gb1     = (const float*)d_in[12];
    const float* gW2     = (const float*)d_in[13];
    const float* gb2     = (const float*)d_in[14];

    char* p = (char*)d_ws;
    auto alloc = [&](size_t bytes) { void* q = (void*)p; p += (bytes + 255) & ~(size_t)255; return q; };
    int*   flags  = (int*)alloc(4 * 4);
    int*   ei32   = (int*)alloc((size_t)2 * EE * 4);
    int*   bat32  = (int*)alloc((size_t)NN * 4);
    bf16*  xb     = (bf16*)alloc((size_t)NN * K1P * 2);
    bf16*  W1tb   = (bf16*)alloc((size_t)DD * K1P * 2);
    bf16*  W2tb   = (bf16*)alloc((size_t)DD * DD * 2);
    bf16*  tsbuf  = (bf16*)alloc((size_t)NN * DD * 2);
    bf16*  hA     = (bf16*)alloc((size_t)NN * DD * 2);
    bf16*  hB     = (bf16*)alloc((size_t)NN * DD * 2);
    bf16*  Bt     = (bf16*)alloc((size_t)LL * DD * HD * 2);
    float* wsbuf  = (float*)alloc((size_t)LL * DD * HH * 4);
    float* wdbuf  = (float*)alloc((size_t)LL * DD * HH * 4);
    float* a_s    = (float*)alloc((size_t)NN * HH * 4);
    float* a_d    = (float*)alloc((size_t)NN * HH * 4);
    int*   deg    = (int*)alloc((size_t)NN * 4);
    int*   start  = (int*)alloc((size_t)(NN + 1) * 4);
    int*   cursor = (int*)alloc((size_t)NN * 4);
    int*   ssrc   = (int*)alloc((size_t)ET * 4);
    int*   bsum   = (int*)alloc((size_t)SB * 4);
    int*   boff   = (int*)alloc((size_t)SB * 4);
    float* pooled = (float*)alloc((size_t)GG * DD * 4);
    int*   counts = (int*)alloc((size_t)GG * 4);
    bf16*  pbf    = (bf16*)alloc((size_t)GG * DD * 2);
    bf16*  gW1t   = (bf16*)alloc((size_t)1024 * DD * 2);
    bf16*  gW2t   = (bf16*)alloc((size_t)DD * 1024 * 2);
    bf16*  t1buf  = (bf16*)alloc((size_t)GG * 1024 * 2);
    size_t need = (size_t)(p - (char*)d_ws);
    if (hostcode == 0 && ws_size < need) hostcode = 34000;

    if (hostcode != 0) {
        sentinel_only<<<1, 64, 0, stream>>>(out, hostcode);
        return;
    }

    detect_i<<<1, 256, 0, stream>>>((const unsigned*)d_in[1], flags + 0);
    detect_i<<<1, 256, 0, stream>>>((const unsigned*)d_in[2], flags + 1);
    conv_i<<<(2 * EE + 255) / 256, 256, 0, stream>>>(d_in[1], ei32, 2 * EE, flags + 0);
    conv_i<<<(NN + 255) / 256, 256, 0, stream>>>(d_in[2], bat32, NN, flags + 1);

    // node MLP via MFMA
    xconv<<<((size_t)NN * K1P + 255) / 256, 256, 0, stream>>>(x, xb);
    nw_conv<<<(DD * K1P + DD * DD + 255) / 256, 256, 0, stream>>>(W1, W2, W1tb, W2tb);
    mlp_gemm1<<<(NN / 16 * 64 + 255) / 256, 256, 0, stream>>>(xb, W1tb, b1, tsbuf);
    mlp_gemm2<<<(NN / 16 * 64 + 255) / 256, 256, 0, stream>>>(tsbuf, W2tb, b2, hA);

    asd_w<<<(LL * DD * HH + 255) / 256, 256, 0, stream>>>(lin_w, att_src, att_dst, wsbuf, wdbuf);
    wt2_conv<<<(LL * DD * HD + 255) / 256, 256, 0, stream>>>(lin_w, Bt);
    gw_conv<<<(2 * 1024 * DD + 255) / 256, 256, 0, stream>>>(gW1, gW2, gW1t, gW2t);
    init_deg<<<(NN + 255) / 256, 256, 0, stream>>>(deg);
    hist_edges<<<(EE + 255) / 256, 256, 0, stream>>>(ei32, deg);
    block_sums<<<SB, 256, 0, stream>>>(deg, bsum);
    scan_bsum<<<1, 256, 0, stream>>>(bsum, boff, start);
    scan_final<<<SB, 256, 0, stream>>>(deg, boff, start, cursor);
    scatter_self<<<(NN + 255) / 256, 256, 0, stream>>>(cursor, ssrc);
    scatter_edges<<<(EE + 255) / 256, 256, 0, stream>>>(ei32, cursor, ssrc);

    bf16* hin = hA;
    bf16* hout = hB;
    for (int l = 0; l < LL; l++) {
        a_sd2<<<(NN + 255) / 256, 256, 0, stream>>>(hin, wsbuf + l * DD * HH, wdbuf + l * DD * HH, a_s, a_d);
        agg_gemm<<<NN / 16, 1024, 0, stream>>>(start, ssrc, a_s, a_d, hin,
                                               Bt + (size_t)l * DD * HD, conv_b + l * DD, hout);
        bf16* tmp = hin; hin = hout; hout = tmp;
    }
    pool_init<<<(GG * DD + 255) / 256, 256, 0, stream>>>(pooled, counts);
    pool_count<<<(NN + 255) / 256, 256, 0, stream>>>(bat32, counts);
    pool_accum2<<<(NN + 63) / 64, 256, 0, stream>>>(hin, bat32, pooled);
    pooled2bf<<<(GG * DD + 255) / 256, 256, 0, stream>>>(pooled, counts, pbf);
    fc1_mfma<<<(64 * 64) / 4, 256, 0, stream>>>(pbf, gW1t, gb1, t1buf);
    fc2_mfma<<<(64 * 8) / 4, 256, 0, stream>>>(t1buf, gW2t, gb2, out);
}

// Round 19
// 649.116 us; speedup vs baseline: 1.2005x; 1.2005x over previous
//
#include <hip/hip_runtime.h>
#include <hip/hip_bf16.h>

#define NN 50000   // nodes
#define EE 800000  // directed edges (no self loops)
#define ET 850000  // EE + NN self loops
#define GG 1024    // graphs
#define DD 128     // embedding dim
#define HH 4       // heads
#define LL 3       // layers
#define ND 78      // node feature dim
#define HD 512     // HH*DD
#define K1P 96     // node-dim padded to multiple of 32 for MFMA
#define SLOPE 0.2f
#define EPSV 1e-16f
#define SB 196     // scan blocks = ceil(NN/256)
#define PADS 520   // LDS row stride in shorts (512 + 8 pad)

typedef __hip_bfloat16 bf16;
typedef __attribute__((ext_vector_type(8))) unsigned short u16x8;
typedef __attribute__((ext_vector_type(8))) short s16x8;   // MFMA A/B fragment (8 bf16)
typedef __attribute__((ext_vector_type(4))) float f32x4;   // MFMA C/D fragment

__device__ __forceinline__ float b2f(bf16 v) { return __bfloat162float(v); }
__device__ __forceinline__ bf16 f2b(float v) { return __float2bfloat16(v); }
__device__ __forceinline__ float bu2f(unsigned short u) {
    return __uint_as_float(((unsigned)u) << 16);
}
__device__ __forceinline__ unsigned short f2bu(float f) {
    unsigned u = __float_as_uint(f);
    unsigned rounded = u + 0x7FFFu + ((u >> 16) & 1u);
    return (unsigned short)(rounded >> 16);
}

// ---------------- int width detection (int64 vs int32) ----------------
__global__ void detect_i(const unsigned* __restrict__ w, int* __restrict__ flag) {
    __shared__ int z;
    int t = threadIdx.x;  // 256
    if (t == 0) z = 0;
    __syncthreads();
    if (w[2 * t + 1] == 0u) atomicAdd(&z, 1);
    __syncthreads();
    if (t == 0) flag[0] = (z >= 200) ? 1 : 0;
}
__global__ void conv_i(const void* __restrict__ src, int* __restrict__ dst, int n,
                       const int* __restrict__ flag) {
    int i = blockIdx.x * 256 + threadIdx.x;
    if (i >= n) return;
    const int* s = (const int*)src;
    dst[i] = flag[0] ? s[2 * i] : s[i];
}

// ---------------- x -> bf16, zero-padded to K1P ----------------
__global__ void xconv(const float* __restrict__ x, bf16* __restrict__ xb) {
    int idx = blockIdx.x * 256 + threadIdx.x;
    if (idx >= NN * K1P) return;
    int n = idx / K1P;
    int k = idx % K1P;
    xb[idx] = f2b((k < ND) ? x[(size_t)n * ND + k] : 0.f);
}
// W1t[c][k<96] = W1[k][c] (zero-pad k>=78); W2t[c][k] = W2[k][c]; bf16
__global__ void nw_conv(const float* __restrict__ W1, const float* __restrict__ W2,
                        bf16* __restrict__ W1t, bf16* __restrict__ W2t) {
    int idx = blockIdx.x * 256 + threadIdx.x;
    if (idx < DD * K1P) {
        int c = idx / K1P, k = idx % K1P;
        W1t[idx] = f2b((k < ND) ? W1[(size_t)k * DD + c] : 0.f);
    }
    idx -= DD * K1P;
    if (idx >= 0 && idx < DD * DD) {
        int c = idx / DD, k = idx % DD;
        W2t[idx] = f2b(W2[(size_t)k * DD + c]);
    }
}

// ---------------- node MLP stage 1: ts = relu(xb[NN,96] @ W1t^T + b1), MFMA ----------------
__global__ __launch_bounds__(256) void mlp_gemm1(const bf16* __restrict__ xb,
                                                 const bf16* __restrict__ W1t,
                                                 const float* __restrict__ b1,
                                                 bf16* __restrict__ ts) {
    int wid = (blockIdx.x * 256 + threadIdx.x) >> 6;
    if (wid >= NN / 16) return;
    int lane = threadIdx.x & 63;
    int r16 = lane & 15;
    int q = lane >> 4;
    const short* ab = (const short*)xb;
    const short* bb = (const short*)W1t;
    int arow = wid * 16 + r16;
    s16x8 afr[3];
#pragma unroll
    for (int c = 0; c < 3; c++) afr[c] = *(const s16x8*)(ab + (size_t)arow * K1P + c * 32 + q * 8);
#pragma unroll
    for (int nt = 0; nt < 8; nt++) {
        int brow = nt * 16 + r16;
        f32x4 acc = {0.f, 0.f, 0.f, 0.f};
#pragma unroll
        for (int c = 0; c < 3; c++) {
            s16x8 b = *(const s16x8*)(bb + (size_t)brow * K1P + c * 32 + q * 8);
            acc = __builtin_amdgcn_mfma_f32_16x16x32_bf16(afr[c], b, acc, 0, 0, 0);
        }
        int cc = nt * 16 + r16;
        float bias = b1[cc];
#pragma unroll
        for (int r = 0; r < 4; r++) {
            int row = wid * 16 + q * 4 + r;
            ts[(size_t)row * DD + cc] = f2b(fmaxf(acc[r] + bias, 0.f));
        }
    }
}

// ---------------- node MLP stage 2: h = ts[NN,128] @ W2t^T + b2, MFMA ----------------
__global__ __launch_bounds__(256) void mlp_gemm2(const bf16* __restrict__ ts,
                                                 const bf16* __restrict__ W2t,
                                                 const float* __restrict__ b2,
                                                 bf16* __restrict__ h) {
    int wid = (blockIdx.x * 256 + threadIdx.x) >> 6;
    if (wid >= NN / 16) return;
    int lane = threadIdx.x & 63;
    int r16 = lane & 15;
    int q = lane >> 4;
    const short* ab = (const short*)ts;
    const short* bb = (const short*)W2t;
    int arow = wid * 16 + r16;
    s16x8 afr[4];
#pragma unroll
    for (int c = 0; c < 4; c++) afr[c] = *(const s16x8*)(ab + (size_t)arow * DD + c * 32 + q * 8);
#pragma unroll
    for (int nt = 0; nt < 8; nt++) {
        int brow = nt * 16 + r16;
        f32x4 acc = {0.f, 0.f, 0.f, 0.f};
#pragma unroll
        for (int c = 0; c < 4; c++) {
            s16x8 b = *(const s16x8*)(bb + (size_t)brow * DD + c * 32 + q * 8);
            acc = __builtin_amdgcn_mfma_f32_16x16x32_bf16(afr[c], b, acc, 0, 0, 0);
        }
        int cc = nt * 16 + r16;
        float bias = b2[cc];
#pragma unroll
        for (int r = 0; r < 4; r++) {
            int row = wid * 16 + q * 4 + r;
            h[(size_t)row * DD + cc] = f2b(acc[r] + bias);
        }
    }
}

// ---------------- counting sort of edges by dst (parallel 3-phase scan) ----------------
__global__ void init_deg(int* deg) {
    int n = blockIdx.x * 256 + threadIdx.x;
    if (n < NN) deg[n] = 1;  // self loop
}
__global__ void hist_edges(const int* __restrict__ ei, int* deg) {
    int e = blockIdx.x * 256 + threadIdx.x;
    if (e >= EE) return;
    int dst = ei[EE + e];
    if ((unsigned)dst < NN) atomicAdd(&deg[dst], 1);
}
__global__ __launch_bounds__(256) void block_sums(const int* __restrict__ deg, int* __restrict__ bsum) {
    __shared__ int part[256];
    int t = threadIdx.x;
    int i = blockIdx.x * 256 + t;
    part[t] = (i < NN) ? deg[i] : 0;
    __syncthreads();
    for (int off = 128; off > 0; off >>= 1) {
        if (t < off) part[t] += part[t + off];
        __syncthreads();
    }
    if (t == 0) bsum[blockIdx.x] = part[0];
}
__global__ __launch_bounds__(256) void scan_bsum(const int* __restrict__ bsum, int* __restrict__ boff,
                                                 int* __restrict__ start) {
    __shared__ int part[256];
    int t = threadIdx.x;
    part[t] = (t < SB) ? bsum[t] : 0;
    __syncthreads();
    for (int off = 1; off < 256; off <<= 1) {
        int add = (t >= off) ? part[t - off] : 0;
        __syncthreads();
        part[t] += add;
        __syncthreads();
    }
    if (t < SB) boff[t] = (t == 0) ? 0 : part[t - 1];
    if (t == 255) start[NN] = part[SB - 1];
}
__global__ __launch_bounds__(256) void scan_final(const int* __restrict__ deg, const int* __restrict__ boff,
                                                  int* __restrict__ start, int* __restrict__ cursor) {
    __shared__ int part[256];
    int t = threadIdx.x;
    int i = blockIdx.x * 256 + t;
    int v = (i < NN) ? deg[i] : 0;
    part[t] = v;
    __syncthreads();
    for (int off = 1; off < 256; off <<= 1) {
        int add = (t >= off) ? part[t - off] : 0;
        __syncthreads();
        part[t] += add;
        __syncthreads();
    }
    if (i < NN) {
        int ex = boff[blockIdx.x] + part[t] - v;
        start[i] = ex;
        cursor[i] = ex;
    }
}
__global__ void scatter_self(int* cursor, int* ssrc) {
    int n = blockIdx.x * 256 + threadIdx.x;
    if (n >= NN) return;
    int pos = atomicAdd(&cursor[n], 1);
    if ((unsigned)pos < ET) ssrc[pos] = n;
}
__global__ void scatter_edges(const int* __restrict__ ei, int* cursor, int* ssrc) {
    int e = blockIdx.x * 256 + threadIdx.x;
    if (e >= EE) return;
    int src = ei[e];
    int dst = ei[EE + e];
    if ((unsigned)dst >= NN) return;
    int pos = atomicAdd(&cursor[dst], 1);
    if ((unsigned)pos < ET) ssrc[pos] = ((unsigned)src < NN) ? src : 0;
}

// ---------------- precompute ws/wd [L][D][H] ----------------
__global__ void asd_w(const float* __restrict__ lin_w, const float* __restrict__ att_src,
                      const float* __restrict__ att_dst,
                      float* __restrict__ ws, float* __restrict__ wd) {
    int idx = blockIdx.x * 256 + threadIdx.x;
    if (idx >= LL * DD * HH) return;
    int l = idx / (DD * HH);
    int rem = idx % (DD * HH);
    int d = rem >> 2;
    int h = rem & 3;
    const float* wrow = lin_w + ((size_t)(l * DD + d) * HH + h) * DD;
    const float* as = att_src + (size_t)(l * HH + h) * DD;
    const float* ad = att_dst + (size_t)(l * HH + h) * DD;
    float s1 = 0.f, s2 = 0.f;
    for (int e = 0; e < DD; e++) { float w = wrow[e]; s1 += w * as[e]; s2 += w * ad[e]; }
    ws[idx] = s1;
    wd[idx] = s2;
}

// ---------------- Bt[l][c][k=h*128+d] = lin_w[l][d][h][c], bf16 ----------------
__global__ void wt2_conv(const float* __restrict__ lin_w, bf16* __restrict__ Bt) {
    int idx = blockIdx.x * 256 + threadIdx.x;
    if (idx >= LL * DD * HD) return;
    int l = idx / (DD * HD);
    int rem = idx % (DD * HD);
    int c = rem / HD;
    int k = rem % HD;
    int h = k >> 7;
    int d = k & 127;
    Bt[idx] = f2b(lin_w[((size_t)(l * DD + d) * HH + h) * DD + c]);
}

// ---------------- gW1t/gW2t transposes (bf16) ----------------
__global__ void gw_conv(const float* __restrict__ gW1, const float* __restrict__ gW2,
                        bf16* __restrict__ gW1t, bf16* __restrict__ gW2t) {
    int idx = blockIdx.x * 256 + threadIdx.x;
    if (idx < 1024 * DD) {
        int c = idx / DD, k = idx % DD;
        gW1t[idx] = f2b(gW1[(size_t)k * 1024 + c]);
    }
    idx -= 1024 * DD;
    if (idx >= 0 && idx < DD * 1024) {
        int c = idx / 1024, k = idx % 1024;
        gW2t[idx] = f2b(gW2[(size_t)k * DD + c]);
    }
}

// ---------------- a_s,a_d from h: one thread per node ----------------
__global__ __launch_bounds__(256) void a_sd2(const bf16* __restrict__ h,
                                             const float* __restrict__ ws,
                                             const float* __restrict__ wd,
                                             float* __restrict__ a_s, float* __restrict__ a_d) {
    __shared__ float wsl[DD][HH];
    __shared__ float wdl[DD][HH];
    int t = threadIdx.x;
    for (int i = t; i < DD * HH; i += 256) { wsl[i >> 2][i & 3] = ws[i]; wdl[i >> 2][i & 3] = wd[i]; }
    __syncthreads();
    int n = blockIdx.x * 256 + t;
    if (n >= NN) return;
    const u16x8* row = (const u16x8*)((const unsigned short*)h + (size_t)n * DD);
    float s1[HH] = {0.f, 0.f, 0.f, 0.f};
    float s2[HH] = {0.f, 0.f, 0.f, 0.f};
    for (int c = 0; c < 16; c++) {
        u16x8 v = row[c];
#pragma unroll
        for (int k = 0; k < 8; k++) {
            int d = c * 8 + k;
            float f = bu2f(v[k]);
#pragma unroll
            for (int hh = 0; hh < HH; hh++) {
                s1[hh] += f * wsl[d][hh];
                s2[hh] += f * wdl[d][hh];
            }
        }
    }
#pragma unroll
    for (int hh = 0; hh < HH; hh++) {
        a_s[n * HH + hh] = s1[hh];
        a_d[n * HH + hh] = s2[hh];
    }
}

// ---------------- edge softmax: single gather round (e cached in regs) ----------------
__global__ __launch_bounds__(256) void edge_weights(const int* __restrict__ start,
                                                    const int* __restrict__ ssrc,
                                                    const float* __restrict__ a_s,
                                                    const float* __restrict__ a_d,
                                                    float* __restrict__ w,
                                                    float* __restrict__ invbuf) {
    int node = (blockIdx.x * 256 + threadIdx.x) >> 6;
    if (node >= NN) return;
    int lane = threadIdx.x & 63;
    int jj = lane & 15;
    int h = lane >> 4;
    int s0 = start[node];
    int deg = start[node + 1] - s0;
    float ad = a_d[node * HH + h];
    float ec[4];
    float mx = -1e30f;
#pragma unroll
    for (int k = 0; k < 4; k++) {
        int j = jj + k * 16;
        float e = -1e30f;
        if (j < deg) {
            int s = ssrc[s0 + j];
            e = a_s[s * HH + h] + ad;
            e = (e > 0.f) ? e : SLOPE * e;
        }
        ec[k] = e;
        mx = fmaxf(mx, e);
    }
    for (int j = jj + 64; j < deg; j += 16) {   // rare fallback
        int s = ssrc[s0 + j];
        float e = a_s[s * HH + h] + ad;
        e = (e > 0.f) ? e : SLOPE * e;
        mx = fmaxf(mx, e);
    }
#pragma unroll
    for (int off = 1; off < 16; off <<= 1) mx = fmaxf(mx, __shfl_xor(mx, off));
    float den = 0.f;
#pragma unroll
    for (int k = 0; k < 4; k++) {
        int j = jj + k * 16;
        if (j < deg) {
            float ww = __expf(ec[k] - mx);
            den += ww;
            w[(size_t)(s0 + j) * HH + h] = ww;
        }
    }
    for (int j = jj + 64; j < deg; j += 16) {   // rare fallback
        int s = ssrc[s0 + j];
        float e = a_s[s * HH + h] + ad;
        e = (e > 0.f) ? e : SLOPE * e;
        float ww = __expf(e - mx);
        den += ww;
        w[(size_t)(s0 + j) * HH + h] = ww;
    }
#pragma unroll
    for (int off = 1; off < 16; off <<= 1) den += __shfl_xor(den, off);
    if (jj == 0) invbuf[node * HH + h] = 1.f / (den + EPSV);
}

// ---------------- fused: aggregate 16 nodes (LDS) + post-GEMM (MFMA) ----------------
// 1024 threads = 16 waves; wave wv aggregates node blockIdx*16+wv into LDS row wv.
// Edge indices for each 64-edge chunk are preloaded with ONE coalesced load
// (sidx = ssrc[s0+c0+lane]) and distributed via __shfl -> all loads in the
// 4-edge unroll (4 h-rows + 4 w-float4s) are independent; 8 in flight/wave.
__global__ __launch_bounds__(1024) void agg_gemm(const int* __restrict__ start,
                                                 const int* __restrict__ ssrc,
                                                 const float* __restrict__ w,
                                                 const float* __restrict__ invbuf,
                                                 const bf16* __restrict__ h,
                                                 const bf16* __restrict__ Bt,
                                                 const float* __restrict__ conv_b,
                                                 bf16* __restrict__ hnext) {
    __shared__ short aggL[16 * PADS];   // 16 rows x 512 (+8 pad) bf16
    int wv = threadIdx.x >> 6;          // 0..15
    int lane = threadIdx.x & 63;
    int node16 = blockIdx.x * 16;
    int node = node16 + wv;             // NN % 16 == 0 -> always valid

    // ---- phase 1: aggregation ----
    int s0 = start[node];
    int deg = start[node + 1] - s0;
    const unsigned* hu = (const unsigned*)h;
    float acc[HH][2];
#pragma unroll
    for (int hh = 0; hh < HH; hh++) { acc[hh][0] = 0.f; acc[hh][1] = 0.f; }

    auto fmaEdge = [&](float4 w4, unsigned hv) {
        float v0 = bu2f((unsigned short)(hv & 0xFFFFu));
        float v1 = bu2f((unsigned short)(hv >> 16));
        acc[0][0] += w4.x * v0; acc[0][1] += w4.x * v1;
        acc[1][0] += w4.y * v0; acc[1][1] += w4.y * v1;
        acc[2][0] += w4.z * v0; acc[2][1] += w4.z * v1;
        acc[3][0] += w4.w * v0; acc[3][1] += w4.w * v1;
    };

    for (int c0 = 0; c0 < deg; c0 += 64) {
        int m = deg - c0; if (m > 64) m = 64;
        int sidx = (c0 + lane < deg) ? ssrc[s0 + c0 + lane] : 0;  // one coalesced load
        int j = 0;
        for (; j + 4 <= m; j += 4) {
            int sA = __shfl(sidx, j);
            int sB = __shfl(sidx, j + 1);
            int sC = __shfl(sidx, j + 2);
            int sD = __shfl(sidx, j + 3);
            int e0 = s0 + c0 + j;
            float4 wA = *(const float4*)(w + (size_t)e0 * HH);
            float4 wB = *(const float4*)(w + (size_t)(e0 + 1) * HH);
            float4 wC = *(const float4*)(w + (size_t)(e0 + 2) * HH);
            float4 wD = *(const float4*)(w + (size_t)(e0 + 3) * HH);
            unsigned hA = hu[(size_t)sA * (DD / 2) + lane];
            unsigned hB = hu[(size_t)sB * (DD / 2) + lane];
            unsigned hC = hu[(size_t)sC * (DD / 2) + lane];
            unsigned hD = hu[(size_t)sD * (DD / 2) + lane];
            fmaEdge(wA, hA);
            fmaEdge(wB, hB);
            fmaEdge(wC, hC);
            fmaEdge(wD, hD);
        }
        for (; j < m; j++) {
            int s = __shfl(sidx, j);
            int e0 = s0 + c0 + j;
            float4 w4 = *(const float4*)(w + (size_t)e0 * HH);
            unsigned hv = hu[(size_t)s * (DD / 2) + lane];
            fmaEdge(w4, hv);
        }
    }
    float4 inv4 = *(const float4*)(invbuf + node * HH);
    float invs[HH] = {inv4.x, inv4.y, inv4.z, inv4.w};
    unsigned* aggU = (unsigned*)aggL;   // row stride PADS/2 = 260 uints
#pragma unroll
    for (int hh = 0; hh < HH; hh++) {
        unsigned packed = (unsigned)f2bu(acc[hh][0] * invs[hh]) |
                          ((unsigned)f2bu(acc[hh][1] * invs[hh]) << 16);
        aggU[wv * (PADS / 2) + hh * (DD / 2) + lane] = packed;
    }
    __syncthreads();

    // ---- phase 2: GEMM, waves 0..7 (one 16x16 col tile each) ----
    if (wv < 8) {
        int nt = wv;
        int r16 = lane & 15;
        int q = lane >> 4;
        const short* bb = (const short*)Bt;
        int brow = nt * 16 + r16;
        f32x4 gacc = {0.f, 0.f, 0.f, 0.f};
#pragma unroll
        for (int c = 0; c < 16; c++) {
            s16x8 a = *(const s16x8*)(aggL + r16 * PADS + c * 32 + q * 8);
            s16x8 b = *(const s16x8*)(bb + (size_t)brow * HD + c * 32 + q * 8);
            gacc = __builtin_amdgcn_mfma_f32_16x16x32_bf16(a, b, gacc, 0, 0, 0);
        }
        int cc = nt * 16 + r16;
        float bias = conv_b[cc];
#pragma unroll
        for (int r = 0; r < 4; r++) {
            int row = node16 + q * 4 + r;
            hnext[(size_t)row * DD + cc] = f2b(0.25f * gacc[r] + bias);
        }
    }
}

// ---------------- global mean pool (segmented: batch is sorted) ----------------
__global__ void pool_init(float* pooled, int* counts) {
    int idx = blockIdx.x * 256 + threadIdx.x;
    if (idx < GG * DD) pooled[idx] = 0.f;
    if (idx < GG) counts[idx] = 0;
}
__global__ void pool_count(const int* __restrict__ batch, int* counts) {
    int n = blockIdx.x * 256 + threadIdx.x;
    if (n >= NN) return;
    int g = batch[n];
    if ((unsigned)g < GG) atomicAdd(&counts[g], 1);
}
__global__ __launch_bounds__(256) void pool_accum2(const bf16* __restrict__ h,
                                                   const int* __restrict__ batch,
                                                   float* pooled) {
    int t = threadIdx.x;
    int d = t & 127;
    int half = t >> 7;
    int n0 = blockIdx.x * 64 + half * 32;
    int n1 = n0 + 32; if (n1 > NN) n1 = NN;
    float acc = 0.f;
    int cur = -1;
    for (int n = n0; n < n1; n++) {
        int g = batch[n];
        if ((unsigned)g >= GG) continue;
        if (g != cur) {
            if (cur >= 0) atomicAdd(&pooled[cur * DD + d], acc);
            acc = 0.f; cur = g;
        }
        acc += b2f(h[(size_t)n * DD + d]);
    }
    if (cur >= 0) atomicAdd(&pooled[cur * DD + d], acc);
}
__global__ void pooled2bf(const float* __restrict__ pooled, const int* __restrict__ counts,
                          bf16* __restrict__ pbf) {
    int idx = blockIdx.x * 256 + threadIdx.x;
    if (idx >= GG * DD) return;
    int g = idx >> 7;
    int c = counts[g]; if (c < 1) c = 1;
    pbf[idx] = f2b(pooled[idx] / (float)c);
}

// ---------------- FC1 MFMA: t1 = relu(pbf[1024,128] @ gW1t^T + gb1), bf16 ----------------
__global__ __launch_bounds__(256) void fc1_mfma(const bf16* __restrict__ pbf,
                                                const bf16* __restrict__ gW1t,
                                                const float* __restrict__ gb1,
                                                bf16* __restrict__ t1) {
    int wid = (blockIdx.x * 256 + threadIdx.x) >> 6;  // 64*64 waves
    int lane = threadIdx.x & 63;
    int mt = wid >> 6;
    int nt = wid & 63;
    int r16 = lane & 15;
    int q = lane >> 4;
    const short* ab = (const short*)pbf;
    const short* bb = (const short*)gW1t;
    f32x4 acc = {0.f, 0.f, 0.f, 0.f};
    int arow = mt * 16 + r16;
    int brow = nt * 16 + r16;
#pragma unroll
    for (int c = 0; c < 4; c++) {
        s16x8 a = *(const s16x8*)(ab + (size_t)arow * DD + c * 32 + q * 8);
        s16x8 b = *(const s16x8*)(bb + (size_t)brow * DD + c * 32 + q * 8);
        acc = __builtin_amdgcn_mfma_f32_16x16x32_bf16(a, b, acc, 0, 0, 0);
    }
    int cc = nt * 16 + r16;
    float bias = gb1[cc];
#pragma unroll
    for (int r = 0; r < 4; r++) {
        int row = mt * 16 + q * 4 + r;
        t1[(size_t)row * 1024 + cc] = f2b(fmaxf(acc[r] + bias, 0.f));
    }
}

// ---------------- FC2 MFMA: out = t1[1024,1024] @ gW2t^T + gb2, f32 ----------------
__global__ __launch_bounds__(256) void fc2_mfma(const bf16* __restrict__ t1,
                                                const bf16* __restrict__ gW2t,
                                                const float* __restrict__ gb2,
                                                float* __restrict__ out) {
    int wid = (blockIdx.x * 256 + threadIdx.x) >> 6;  // 64*8 waves
    int lane = threadIdx.x & 63;
    int mt = wid >> 3;
    int nt = wid & 7;
    int r16 = lane & 15;
    int q = lane >> 4;
    const short* ab = (const short*)t1;
    const short* bb = (const short*)gW2t;
    f32x4 acc = {0.f, 0.f, 0.f, 0.f};
    int arow = mt * 16 + r16;
    int brow = nt * 16 + r16;
#pragma unroll
    for (int c = 0; c < 32; c++) {
        s16x8 a = *(const s16x8*)(ab + (size_t)arow * 1024 + c * 32 + q * 8);
        s16x8 b = *(const s16x8*)(bb + (size_t)brow * 1024 + c * 32 + q * 8);
        acc = __builtin_amdgcn_mfma_f32_16x16x32_bf16(a, b, acc, 0, 0, 0);
    }
    int cc = nt * 16 + r16;
    float bias = gb2[cc];
#pragma unroll
    for (int r = 0; r < 4; r++) {
        int row = mt * 16 + q * 4 + r;
        out[(size_t)row * DD + cc] = acc[r] + bias;
    }
}

__global__ void sentinel_only(float* out, int hostcode) {
    if (threadIdx.x == 0 && blockIdx.x == 0) out[0] = (float)hostcode;
}

extern "C" void kernel_launch(void* const* d_in, const int* in_sizes, int n_in,
                              void* d_out, int out_size, void* d_ws, size_t ws_size,
                              hipStream_t stream) {
    float* out = (float*)d_out;

    static const int expect[15] = {3900000, 1600000, 50000, 9984, 128, 16384, 128,
                                   196608, 1536, 1536, 384, 131072, 1024, 131072, 128};
    int hostcode = 0;
    if (n_in != 15) hostcode = 21099;
    else for (int i = 0; i < 15; i++) if (in_sizes[i] != expect[i]) { hostcode = 21000 + i; break; }
    if (hostcode == 0 && out_size != GG * DD) hostcode = 35000;

    const float* x       = (const float*)d_in[0];
    const float* W1      = (const float*)d_in[3];
    const float* b1      = (const float*)d_in[4];
    const float* W2      = (const float*)d_in[5];
    const float* b2      = (const float*)d_in[6];
    const float* lin_w   = (const float*)d_in[7];
    const float* att_src = (const float*)d_in[8];
    const float* att_dst = (const float*)d_in[9];
    const float* conv_b  = (const float*)d_in[10];
    const float* gW1     = (const float*)d_in[11];
    const float* gb1     = (const float*)d_in[12];
    const float* gW2     = (const float*)d_in[13];
    const float* gb2     = (const float*)d_in[14];

    char* p = (char*)d_ws;
    auto alloc = [&](size_t bytes) { void* q = (void*)p; p += (bytes + 255) & ~(size_t)255; return q; };
    int*   flags  = (int*)alloc(4 * 4);
    int*   ei32   = (int*)alloc((size_t)2 * EE * 4);
    int*   bat32  = (int*)alloc((size_t)NN * 4);
    bf16*  xb     = (bf16*)alloc((size_t)NN * K1P * 2);
    bf16*  W1tb   = (bf16*)alloc((size_t)DD * K1P * 2);
    bf16*  W2tb   = (bf16*)alloc((size_t)DD * DD * 2);
    bf16*  tsbuf  = (bf16*)alloc((size_t)NN * DD * 2);
    bf16*  hA     = (bf16*)alloc((size_t)NN * DD * 2);
    bf16*  hB     = (bf16*)alloc((size_t)NN * DD * 2);
    bf16*  Bt     = (bf16*)alloc((size_t)LL * DD * HD * 2);
    float* wsbuf  = (float*)alloc((size_t)LL * DD * HH * 4);
    float* wdbuf  = (float*)alloc((size_t)LL * DD * HH * 4);
    float* a_s    = (float*)alloc((size_t)NN * HH * 4);
    float* a_d    = (float*)alloc((size_t)NN * HH * 4);
    float* wbuf   = (float*)alloc((size_t)ET * HH * 4);
    float* invbuf = (float*)alloc((size_t)NN * HH * 4);
    int*   deg    = (int*)alloc((size_t)NN * 4);
    int*   start  = (int*)alloc((size_t)(NN + 1) * 4);
    int*   cursor = (int*)alloc((size_t)NN * 4);
    int*   ssrc   = (int*)alloc((size_t)ET * 4);
    int*   bsum   = (int*)alloc((size_t)SB * 4);
    int*   boff   = (int*)alloc((size_t)SB * 4);
    float* pooled = (float*)alloc((size_t)GG * DD * 4);
    int*   counts = (int*)alloc((size_t)GG * 4);
    bf16*  pbf    = (bf16*)alloc((size_t)GG * DD * 2);
    bf16*  gW1t   = (bf16*)alloc((size_t)1024 * DD * 2);
    bf16*  gW2t   = (bf16*)alloc((size_t)DD * 1024 * 2);
    bf16*  t1buf  = (bf16*)alloc((size_t)GG * 1024 * 2);
    size_t need = (size_t)(p - (char*)d_ws);
    if (hostcode == 0 && ws_size < need) hostcode = 34000;

    if (hostcode != 0) {
        sentinel_only<<<1, 64, 0, stream>>>(out, hostcode);
        return;
    }

    detect_i<<<1, 256, 0, stream>>>((const unsigned*)d_in[1], flags + 0);
    detect_i<<<1, 256, 0, stream>>>((const unsigned*)d_in[2], flags + 1);
    conv_i<<<(2 * EE + 255) / 256, 256, 0, stream>>>(d_in[1], ei32, 2 * EE, flags + 0);
    conv_i<<<(NN + 255) / 256, 256, 0, stream>>>(d_in[2], bat32, NN, flags + 1);

    // node MLP via MFMA
    xconv<<<((size_t)NN * K1P + 255) / 256, 256, 0, stream>>>(x, xb);
    nw_conv<<<(DD * K1P + DD * DD + 255) / 256, 256, 0, stream>>>(W1, W2, W1tb, W2tb);
    mlp_gemm1<<<(NN / 16 * 64 + 255) / 256, 256, 0, stream>>>(xb, W1tb, b1, tsbuf);
    mlp_gemm2<<<(NN / 16 * 64 + 255) / 256, 256, 0, stream>>>(tsbuf, W2tb, b2, hA);

    asd_w<<<(LL * DD * HH + 255) / 256, 256, 0, stream>>>(lin_w, att_src, att_dst, wsbuf, wdbuf);
    wt2_conv<<<(LL * DD * HD + 255) / 256, 256, 0, stream>>>(lin_w, Bt);
    gw_conv<<<(2 * 1024 * DD + 255) / 256, 256, 0, stream>>>(gW1, gW2, gW1t, gW2t);
    init_deg<<<(NN + 255) / 256, 256, 0, stream>>>(deg);
    hist_edges<<<(EE + 255) / 256, 256, 0, stream>>>(ei32, deg);
    block_sums<<<SB, 256, 0, stream>>>(deg, bsum);
    scan_bsum<<<1, 256, 0, stream>>>(bsum, boff, start);
    scan_final<<<SB, 256, 0, stream>>>(deg, boff, start, cursor);
    scatter_self<<<(NN + 255) / 256, 256, 0, stream>>>(cursor, ssrc);
    scatter_edges<<<(EE + 255) / 256, 256, 0, stream>>>(ei32, cursor, ssrc);

    const int NWB = (NN * 64 + 255) / 256;  // wave-per-node grids
    bf16* hin = hA;
    bf16* hout = hB;
    for (int l = 0; l < LL; l++) {
        a_sd2<<<(NN + 255) / 256, 256, 0, stream>>>(hin, wsbuf + l * DD * HH, wdbuf + l * DD * HH, a_s, a_d);
        edge_weights<<<NWB, 256, 0, stream>>>(start, ssrc, a_s, a_d, wbuf, invbuf);
        agg_gemm<<<NN / 16, 1024, 0, stream>>>(start, ssrc, wbuf, invbuf, hin,
                                               Bt + (size_t)l * DD * HD, conv_b + l * DD, hout);
        bf16* tmp = hin; hin = hout; hout = tmp;
    }
    pool_init<<<(GG * DD + 255) / 256, 256, 0, stream>>>(pooled, counts);
    pool_count<<<(NN + 255) / 256, 256, 0, stream>>>(bat32, counts);
    pool_accum2<<<(NN + 63) / 64, 256, 0, stream>>>(hin, bat32, pooled);
    pooled2bf<<<(GG * DD + 255) / 256, 256, 0, stream>>>(pooled, counts, pbf);
    fc1_mfma<<<(64 * 64) / 4, 256, 0, stream>>>(pbf, gW1t, gb1, t1buf);
    fc2_mfma<<<(64 * 8) / 4, 256, 0, stream>>>(t1buf, gW2t, gb2, out);
}